// Round 2
// baseline (290.576 us; speedup 1.0000x reference)
//
#include <hip/hip_runtime.h>

// LaplacianRegularizer3D: sum over 27 shifts (dk,di,dj) in {-1,0,1}^3 of
// sum((x[p]-x[p+s])^2) over x = f.reshape(8,12,8,256,256).
// Equivalent: 2 * sum over 13 forward shifts:
//   S13 = {(1,0,0)} u {(dk,0,1)} u {(dk,1,dj)},  dk,dj in {-1,0,1}
// Only rows i and i+1 are needed; k (D=8) planes all held in registers.
// One wave == one full row (64 lanes x float4 = 256 elems); j-edges via shuffle.

constexpr int WIDTH = 256;
constexpr int HWs   = 256 * 256;

__global__ __launch_bounds__(256, 2) void lap3d(const float* __restrict__ f,
                                                float* __restrict__ out) {
    const int tid  = threadIdx.x;
    const int lane = tid & 63;
    const int wid  = tid >> 6;
    const int row  = blockIdx.x * 4 + wid;   // 0..24575 = (b*12+c)*256 + i
    const int i    = row & 255;
    const int bc   = row >> 8;               // 0..95
    const float* base = f + (size_t)bc * 8 * HWs + (size_t)i * WIDTH + (size_t)lane * 4;

    const bool has_down  = (i < 255);
    const bool has_right = (lane < 63);  // j0+4 < 256
    const bool has_left  = (lane > 0);   // j0-1 >= 0

    float o[8][4], nx[8][4];
#pragma unroll
    for (int k = 0; k < 8; ++k) {
        float4 v = *reinterpret_cast<const float4*>(base + k * HWs);
        o[k][0] = v.x; o[k][1] = v.y; o[k][2] = v.z; o[k][3] = v.w;
    }
    if (has_down) {
#pragma unroll
        for (int k = 0; k < 8; ++k) {
            float4 v = *reinterpret_cast<const float4*>(base + k * HWs + WIDTH);
            nx[k][0] = v.x; nx[k][1] = v.y; nx[k][2] = v.z; nx[k][3] = v.w;
        }
    } else {
#pragma unroll
        for (int k = 0; k < 8; ++k) { nx[k][0] = nx[k][1] = nx[k][2] = nx[k][3] = 0.f; }
    }

    // j-edge values from neighboring lanes (wave spans the whole row)
    float eo[8], nl[8], nr[8];
#pragma unroll
    for (int k = 0; k < 8; ++k) {
        eo[k] = __shfl_down(o[k][0], 1);   // own row, j0+4
        nr[k] = __shfl_down(nx[k][0], 1);  // row i+1, j0+4
        nl[k] = __shfl_up(nx[k][3], 1);    // row i+1, j0-1
    }

    float acc = 0.f;

    // s = (1,0,0): o[k] vs o[k+1]
#pragma unroll
    for (int k = 0; k < 7; ++k)
#pragma unroll
        for (int m = 0; m < 4; ++m) { float d = o[k][m] - o[k + 1][m]; acc += d * d; }

    // s = (dk,0,1): o[k][j] vs o[k+dk][j+1]
#pragma unroll
    for (int k = 0; k < 8; ++k)
#pragma unroll
        for (int dk = -1; dk <= 1; ++dk) {
            const int kk = k + dk;
            if (kk < 0 || kk > 7) continue;
#pragma unroll
            for (int m = 0; m < 3; ++m) { float d = o[k][m] - o[kk][m + 1]; acc += d * d; }
            if (has_right) { float d = o[k][3] - eo[kk]; acc += d * d; }
        }

    // s = (dk,1,dj): o[k][i][j] vs plane k+dk, row i+1, col j+dj
    if (has_down) {
#pragma unroll
        for (int k = 0; k < 8; ++k)
#pragma unroll
            for (int dk = -1; dk <= 1; ++dk) {
                const int kk = k + dk;
                if (kk < 0 || kk > 7) continue;
                // dj = 0
#pragma unroll
                for (int m = 0; m < 4; ++m) { float d = o[k][m] - nx[kk][m]; acc += d * d; }
                // dj = +1
#pragma unroll
                for (int m = 0; m < 3; ++m) { float d = o[k][m] - nx[kk][m + 1]; acc += d * d; }
                if (has_right) { float d = o[k][3] - nr[kk]; acc += d * d; }
                // dj = -1
#pragma unroll
                for (int m = 1; m < 4; ++m) { float d = o[k][m] - nx[kk][m - 1]; acc += d * d; }
                if (has_left) { float d = o[k][0] - nl[kk]; acc += d * d; }
            }
    }

    // Wave reduce (64 lanes), then cross-wave via LDS, one atomic per block.
#pragma unroll
    for (int off = 32; off > 0; off >>= 1) acc += __shfl_down(acc, off);

    __shared__ float wsum[4];
    if (lane == 0) wsum[wid] = acc;
    __syncthreads();
    if (tid == 0) {
        float s = wsum[0] + wsum[1] + wsum[2] + wsum[3];
        atomicAdd(out, 2.0f * s);   // x2: forward shifts only
    }
}

extern "C" void kernel_launch(void* const* d_in, const int* in_sizes, int n_in,
                              void* d_out, int out_size, void* d_ws, size_t ws_size,
                              hipStream_t stream) {
    const float* f = (const float*)d_in[0];
    float* out = (float*)d_out;
    hipMemsetAsync(out, 0, sizeof(float), stream);          // d_out is poisoned 0xAA
    const int rows = 8 * 12 * 256;                           // 24576
    lap3d<<<dim3(rows / 4), dim3(256), 0, stream>>>(f, out);
}

// Round 3
// 272.332 us; speedup vs baseline: 1.0670x; 1.0670x over previous
//
#include <hip/hip_runtime.h>

// LaplacianRegularizer3D: sum over 27 shifts (dk,di,dj) in {-1,0,1}^3 of
// sum((x[p]-x[p+s])^2) over x = f.reshape(8,12,8,256,256).
// = 2 * sum over 13 forward shifts:
//   S13 = {(1,0,0)} u {(dk,0,1)} u {(dk,1,dj)},  dk,dj in {-1,0,1}
// One wave == one full row (64 lanes x float4 = 256 elems); all 8 k-planes in
// registers; j-edges via shuffle. Two-stage reduction: block partials -> d_ws,
// then a 1-block kernel sums 6144 partials (no same-address atomics at all).

constexpr int WIDTH  = 256;
constexpr int HWs    = 256 * 256;
constexpr int NBLOCK = 8 * 12 * 256 / 4;   // 6144

__global__ __launch_bounds__(256, 2) void lap3d(const float* __restrict__ f,
                                                float* __restrict__ partial) {
    const int tid  = threadIdx.x;
    const int lane = tid & 63;
    const int wid  = tid >> 6;
    const int row  = blockIdx.x * 4 + wid;   // (b*12+c)*256 + i
    const int i    = row & 255;
    const int bc   = row >> 8;               // 0..95
    const float* base = f + (size_t)bc * 8 * HWs + (size_t)i * WIDTH + (size_t)lane * 4;

    const bool has_down  = (i < 255);
    const bool has_right = (lane < 63);
    const bool has_left  = (lane > 0);

    float o[8][4], nx[8][4];
#pragma unroll
    for (int k = 0; k < 8; ++k) {
        float4 v = *reinterpret_cast<const float4*>(base + k * HWs);
        o[k][0] = v.x; o[k][1] = v.y; o[k][2] = v.z; o[k][3] = v.w;
    }
    if (has_down) {
#pragma unroll
        for (int k = 0; k < 8; ++k) {
            float4 v = *reinterpret_cast<const float4*>(base + k * HWs + WIDTH);
            nx[k][0] = v.x; nx[k][1] = v.y; nx[k][2] = v.z; nx[k][3] = v.w;
        }
    } else {
#pragma unroll
        for (int k = 0; k < 8; ++k) { nx[k][0] = nx[k][1] = nx[k][2] = nx[k][3] = 0.f; }
    }

    // j-edge values from neighboring lanes (wave spans the whole row)
    float eo[8], nl[8], nr[8];
#pragma unroll
    for (int k = 0; k < 8; ++k) {
        eo[k] = __shfl_down(o[k][0], 1);   // own row, j0+4
        nr[k] = __shfl_down(nx[k][0], 1);  // row i+1, j0+4
        nl[k] = __shfl_up(nx[k][3], 1);    // row i+1, j0-1
    }

    float acc = 0.f;

    // s = (1,0,0)
#pragma unroll
    for (int k = 0; k < 7; ++k)
#pragma unroll
        for (int m = 0; m < 4; ++m) { float d = o[k][m] - o[k + 1][m]; acc += d * d; }

    // s = (dk,0,1)
#pragma unroll
    for (int k = 0; k < 8; ++k)
#pragma unroll
        for (int dk = -1; dk <= 1; ++dk) {
            const int kk = k + dk;
            if (kk < 0 || kk > 7) continue;
#pragma unroll
            for (int m = 0; m < 3; ++m) { float d = o[k][m] - o[kk][m + 1]; acc += d * d; }
            if (has_right) { float d = o[k][3] - eo[kk]; acc += d * d; }
        }

    // s = (dk,1,dj)
    if (has_down) {
#pragma unroll
        for (int k = 0; k < 8; ++k)
#pragma unroll
            for (int dk = -1; dk <= 1; ++dk) {
                const int kk = k + dk;
                if (kk < 0 || kk > 7) continue;
#pragma unroll
                for (int m = 0; m < 4; ++m) { float d = o[k][m] - nx[kk][m]; acc += d * d; }
#pragma unroll
                for (int m = 0; m < 3; ++m) { float d = o[k][m] - nx[kk][m + 1]; acc += d * d; }
                if (has_right) { float d = o[k][3] - nr[kk]; acc += d * d; }
#pragma unroll
                for (int m = 1; m < 4; ++m) { float d = o[k][m] - nx[kk][m - 1]; acc += d * d; }
                if (has_left) { float d = o[k][0] - nl[kk]; acc += d * d; }
            }
    }

    // Wave reduce, cross-wave via LDS, one partial per block (no atomics).
#pragma unroll
    for (int off = 32; off > 0; off >>= 1) acc += __shfl_down(acc, off);

    __shared__ float wsum[4];
    if (lane == 0) wsum[wid] = acc;
    __syncthreads();
    if (tid == 0) partial[blockIdx.x] = wsum[0] + wsum[1] + wsum[2] + wsum[3];
}

__global__ __launch_bounds__(256) void lap3d_reduce(const float* __restrict__ partial,
                                                    float* __restrict__ out) {
    float s = 0.f;
    for (int i = threadIdx.x; i < NBLOCK; i += 256) s += partial[i];
#pragma unroll
    for (int off = 32; off > 0; off >>= 1) s += __shfl_down(s, off);
    __shared__ float w[4];
    if ((threadIdx.x & 63) == 0) w[threadIdx.x >> 6] = s;
    __syncthreads();
    if (threadIdx.x == 0) out[0] = 2.0f * (w[0] + w[1] + w[2] + w[3]); // x2: forward shifts
}

extern "C" void kernel_launch(void* const* d_in, const int* in_sizes, int n_in,
                              void* d_out, int out_size, void* d_ws, size_t ws_size,
                              hipStream_t stream) {
    const float* f = (const float*)d_in[0];
    float* partial = (float*)d_ws;            // 6144 floats, well under ws_size
    float* out = (float*)d_out;
    lap3d<<<dim3(NBLOCK), dim3(256), 0, stream>>>(f, partial);
    lap3d_reduce<<<dim3(1), dim3(256), 0, stream>>>(partial, out);
}